// Round 11
// baseline (109.180 us; speedup 1.0000x reference)
//
#include <hip/hip_runtime.h>
#include <hip/hip_cooperative_groups.h>

namespace cg = cooperative_groups;

#define CS 384
#define CH 32
#define CZ 128
#define LL 512
#define C4 (CZ * CH)   // 4096 combined (z,a) columns
#define EPSV 1e-5f

typedef __attribute__((ext_vector_type(8))) short bf16x8;
typedef __attribute__((ext_vector_type(4))) float f32x4;

static __device__ __forceinline__ unsigned short f2bf(float x) {
  union { float f; unsigned int u; } c; c.f = x;
  unsigned int r = c.u + 0x7FFFu + ((c.u >> 16) & 1u);  // RNE
  return (unsigned short)(r >> 16);
}
static __device__ __forceinline__ unsigned int pk2(float lo, float hi) {
  return (unsigned int)f2bf(lo) | ((unsigned int)f2bf(hi) << 16);
}

// ---- Single cooperative kernel: phase A (LN+proj, Wt transpose) ->
//      grid.sync -> phase B (tmat) -> grid.sync -> phase C (outer, R8 struct).
__global__ __launch_bounds__(512) void mega_kernel(
    const float* __restrict__ s, const float* __restrict__ gamma,
    const float* __restrict__ beta,
    const float* __restrict__ w1, const float* __restrict__ b1,
    const float* __restrict__ w2, const float* __restrict__ b2,
    const float* __restrict__ w_out, const float* __restrict__ b_out,
    unsigned short* __restrict__ Abf, unsigned short* __restrict__ Bbf,
    unsigned short* __restrict__ Wt, unsigned short* __restrict__ Tt,
    float* __restrict__ out) {
  cg::grid_group grid = cg::this_grid();
  int n = blockIdx.x;      // 0..255
  int tid = threadIdx.x;   // 0..511
  __shared__ union {
    struct { float sn[2][CS]; float red[2][256]; float wred[2][8]; } ln;
    float wl[CH * CZ];
  } sm;

  // ================= Phase A: LayerNorm + projections (2 rows/block) ========
  {
    int g = tid >> 8;        // sub-group 0/1 -> row
    int t = tid & 255;
    int l = 2 * n + g;
    const float* srow = s + (size_t)l * CS;
    float lsum = 0.f, lsq = 0.f;
    for (int c = t; c < CS; c += 256) {
      float x = srow[c]; sm.ln.sn[g][c] = x; lsum += x; lsq += x * x;
    }
    #pragma unroll
    for (int off = 32; off > 0; off >>= 1) {
      lsum += __shfl_down(lsum, off);
      lsq  += __shfl_down(lsq, off);
    }
    int wv = t >> 6;  // wave within sub-group 0..3
    if ((t & 63) == 0) { sm.ln.wred[g][wv] = lsum; sm.ln.wred[g][4 + wv] = lsq; }
    __syncthreads();
    float s1 = sm.ln.wred[g][0] + sm.ln.wred[g][1] + sm.ln.wred[g][2] + sm.ln.wred[g][3];
    float s2 = sm.ln.wred[g][4] + sm.ln.wred[g][5] + sm.ln.wred[g][6] + sm.ln.wred[g][7];
    float mu = s1 * (1.0f / CS);
    float var = s2 * (1.0f / CS) - mu * mu;
    float rstd = rsqrtf(var + EPSV);

    for (int c = t; c < CS; c += 256)
      sm.ln.sn[g][c] = (sm.ln.sn[g][c] - mu) * rstd * gamma[c] + beta[c];
    __syncthreads();

    int o = t & 63, qc = t >> 6;
    int h = o & 31;
    const float* w = (o < CH) ? w1 : w2;
    float acc = 0.f;
    int c0 = qc * 96;
    #pragma unroll 8
    for (int c = c0; c < c0 + 96; ++c) acc += sm.ln.sn[g][c] * w[c * CH + h];
    sm.ln.red[g][t] = acc; __syncthreads();
    if (t < 64) {
      float r = sm.ln.red[g][t] + sm.ln.red[g][t + 64] + sm.ln.red[g][t + 128] +
                sm.ln.red[g][t + 192];
      if (o < CH) Abf[l * CH + h] = f2bf(r + b1[h]);
      else        Bbf[l * CH + h] = f2bf(r + b2[h]);
    }
  }
  __syncthreads();

  // ================= Phase A2: Wt transpose (blocks 0..31, a = n) ===========
  if (n < CH) {
    int a = n;
    const float4* Wg = (const float4*)(w_out + (size_t)a * CH * CZ);
    float4* Wl4 = (float4*)sm.wl;
    #pragma unroll
    for (int v = 0; v < 2; ++v) Wl4[tid + v * 512] = Wg[tid + v * 512];
    __syncthreads();
    if (tid < 256) {
      int z = tid >> 1, bh = tid & 1;  // z 0..127, b-half 0..1
      unsigned int dw[8];
      #pragma unroll
      for (int k = 0; k < 8; ++k) {
        unsigned short lo = f2bf(sm.wl[(bh * 16 + 2 * k) * CZ + z]);
        unsigned short hi = f2bf(sm.wl[(bh * 16 + 2 * k + 1) * CZ + z]);
        dw[k] = (unsigned int)lo | ((unsigned int)hi << 16);
      }
      unsigned int* dst =
          (unsigned int*)((char*)Wt + ((size_t)z * CH + a) * 64 + bh * 32);
      *(uint4*)dst = make_uint4(dw[0], dw[1], dw[2], dw[3]);
      *(uint4*)(dst + 4) = make_uint4(dw[4], dw[5], dw[6], dw[7]);
    }
  }

  grid.sync();

  // ================= Phase B: Tt[j][c] = sum_b B[j,b] * Wt[c,b] =============
  {
    int wgid = n * 8 + (tid >> 6);   // 0..2047; use first 1024
    if (wgid < 1024) {
      int jt = wgid >> 5;            // 0..31 -> 16 j's
      int cq = wgid & 31;            // 0..31 -> 128 c's
      int l = tid & 63;
      int q = l >> 4, r = l & 15;
      bf16x8 bfrag = *(const bf16x8*)(Bbf + (size_t)(jt * 16 + r) * CH + 8 * q);
      int j = jt * 16 + r;
      bf16x8 wfrag[8];
      #pragma unroll
      for (int t = 0; t < 8; ++t)
        wfrag[t] = *(const bf16x8*)(Wt + (size_t)(cq * 128 + t * 16 + r) * CH + 8 * q);
      f32x4 zer = {0.f, 0.f, 0.f, 0.f};
      #pragma unroll
      for (int t = 0; t < 8; ++t) {
        int cbase = cq * 128 + t * 16;
        f32x4 acc = __builtin_amdgcn_mfma_f32_16x16x32_bf16(wfrag[t], bfrag, zer, 0, 0, 0);
        uint2 st;
        st.x = pk2(acc[0], acc[1]);
        st.y = pk2(acc[2], acc[3]);
        *(uint2*)(&Tt[(size_t)j * C4 + cbase + 4 * q]) = st;
      }
    }
  }

  grid.sync();

  // ================= Phase C: out[i,j,:] = A[i,:] . T[j,:,:] + b_out ========
  // R8 structure: block owns (16 i) x (64 j, XCD-affine jt); wave w owns 8
  // consecutive j, loops serially. No LDS, no barriers.
  {
    int jt = n & 7;
    int it = n >> 3;
    int w = tid >> 6, l = tid & 63, q = l >> 4, r = l & 15;
    int ib = it * 16;

    bf16x8 af = *(const bf16x8*)(Abf + (size_t)(ib + r) * CH + 8 * q);

    f32x4 bo[8];
    #pragma unroll
    for (int zt = 0; zt < 8; ++zt)
      bo[zt] = *(const f32x4*)(b_out + zt * 16 + 4 * q);

    int j0 = jt * 64 + w * 8;
    float* orow = out + ((size_t)ib + r) * LL * CZ;

    #pragma unroll 2
    for (int jj = 0; jj < 8; ++jj) {
      int j = j0 + jj;
      const unsigned short* Tj = Tt + (size_t)j * C4;
      float* oj = orow + (size_t)j * CZ;
      #pragma unroll
      for (int zt = 0; zt < 8; ++zt) {
        bf16x8 tf = *(const bf16x8*)(Tj + (size_t)(zt * 16 + r) * CH + 8 * q);
        // D = Tt^T(z x a) . A(a x i) + bias: col=r -> i, rows 4q+reg -> z.
        f32x4 d = __builtin_amdgcn_mfma_f32_16x16x32_bf16(tf, af, bo[zt], 0, 0, 0);
        *(f32x4*)(oj + zt * 16 + 4 * q) = d;
      }
    }
  }
}

extern "C" void kernel_launch(void* const* d_in, const int* in_sizes, int n_in,
                              void* d_out, int out_size, void* d_ws, size_t ws_size,
                              hipStream_t stream) {
  const float* s     = (const float*)d_in[0];
  const float* gam   = (const float*)d_in[1];
  const float* bet   = (const float*)d_in[2];
  const float* w1    = (const float*)d_in[3];
  const float* b1    = (const float*)d_in[4];
  const float* w2    = (const float*)d_in[5];
  const float* b2    = (const float*)d_in[6];
  const float* w_out = (const float*)d_in[7];
  const float* b_out = (const float*)d_in[8];
  float* out = (float*)d_out;

  char* ws = (char*)d_ws;
  unsigned short* Abf = (unsigned short*)(ws);            // 32 KB
  unsigned short* Bbf = (unsigned short*)(ws + 32768);    // 32 KB
  unsigned short* Wt  = (unsigned short*)(ws + 65536);    // 256 KB
  unsigned short* Tt  = (unsigned short*)(ws + 327680);   // 4 MB

  void* args[] = {(void*)&s, (void*)&gam, (void*)&bet, (void*)&w1, (void*)&b1,
                  (void*)&w2, (void*)&b2, (void*)&w_out, (void*)&b_out,
                  (void*)&Abf, (void*)&Bbf, (void*)&Wt, (void*)&Tt, (void*)&out};
  hipLaunchCooperativeKernel((void*)mega_kernel, dim3(256), dim3(512), args, 0,
                             stream);
}

// Round 12
// 65.625 us; speedup vs baseline: 1.6637x; 1.6637x over previous
//
#include <hip/hip_runtime.h>

#define CS 384
#define CH 32
#define CZ 128
#define LL 512
#define C4 (CZ * CH)   // 4096 combined (z,a) columns
#define EPSV 1e-5f

typedef __attribute__((ext_vector_type(8))) short bf16x8;
typedef __attribute__((ext_vector_type(4))) float f32x4;

static __device__ __forceinline__ unsigned short f2bf(float x) {
  union { float f; unsigned int u; } c; c.f = x;
  unsigned int r = c.u + 0x7FFFu + ((c.u >> 16) & 1u);  // RNE
  return (unsigned short)(r >> 16);
}
static __device__ __forceinline__ unsigned int pk2(float lo, float hi) {
  return (unsigned int)f2bf(lo) | ((unsigned int)f2bf(hi) << 16);
}

// ---------------- Kernel 1: [blocks 0..511] LayerNorm+proj -> bf16 A,B --------
// ----------------           [blocks 512..543] W transpose -> bf16 Wt ----------
__global__ __launch_bounds__(256) void prep_kernel(
    const float* __restrict__ s, const float* __restrict__ gamma,
    const float* __restrict__ beta,
    const float* __restrict__ w1, const float* __restrict__ b1,
    const float* __restrict__ w2, const float* __restrict__ b2,
    const float* __restrict__ w_out,
    unsigned short* __restrict__ Abf, unsigned short* __restrict__ Bbf,
    unsigned short* __restrict__ Wt) {
  __shared__ union {
    struct { float sn[CS]; float red[256]; float wred[8]; } ln;
    float wl[CH * CZ];
  } sm;
  int tid = threadIdx.x;

  if (blockIdx.x < LL) {
    int l = blockIdx.x;
    const float* srow = s + l * CS;
    float lsum = 0.f, lsq = 0.f;
    for (int c = tid; c < CS; c += 256) {
      float x = srow[c]; sm.ln.sn[c] = x; lsum += x; lsq += x * x;
    }
    #pragma unroll
    for (int off = 32; off > 0; off >>= 1) {
      lsum += __shfl_down(lsum, off);
      lsq  += __shfl_down(lsq, off);
    }
    int wv = tid >> 6;
    if ((tid & 63) == 0) { sm.ln.wred[wv] = lsum; sm.ln.wred[4 + wv] = lsq; }
    __syncthreads();
    float s1 = sm.ln.wred[0] + sm.ln.wred[1] + sm.ln.wred[2] + sm.ln.wred[3];
    float s2 = sm.ln.wred[4] + sm.ln.wred[5] + sm.ln.wred[6] + sm.ln.wred[7];
    float mu = s1 * (1.0f / CS);
    float var = s2 * (1.0f / CS) - mu * mu;
    float rstd = rsqrtf(var + EPSV);

    for (int c = tid; c < CS; c += 256)
      sm.ln.sn[c] = (sm.ln.sn[c] - mu) * rstd * gamma[c] + beta[c];
    __syncthreads();

    int o = tid & 63, q = tid >> 6;
    int h = o & 31;
    const float* w = (o < CH) ? w1 : w2;
    float acc = 0.f;
    int c0 = q * 96;
    #pragma unroll 8
    for (int c = c0; c < c0 + 96; ++c) acc += sm.ln.sn[c] * w[c * CH + h];
    sm.ln.red[tid] = acc; __syncthreads();
    if (tid < 64) {
      float r = sm.ln.red[tid] + sm.ln.red[tid + 64] + sm.ln.red[tid + 128] +
                sm.ln.red[tid + 192];
      if (o < CH) Abf[l * CH + h] = f2bf(r + b1[h]);
      else        Bbf[l * CH + h] = f2bf(r + b2[h]);
    }
  } else {
    int a = blockIdx.x - LL;  // 0..31
    const float4* Wg = (const float4*)(w_out + (size_t)a * CH * CZ);
    float4* Wl4 = (float4*)sm.wl;
    #pragma unroll
    for (int v = 0; v < 4; ++v) Wl4[tid + v * 256] = Wg[tid + v * 256];
    __syncthreads();
    int z = tid >> 1, bh = tid & 1;  // z 0..127, b-half 0..1
    unsigned int dw[8];
    #pragma unroll
    for (int k = 0; k < 8; ++k) {
      unsigned short lo = f2bf(sm.wl[(bh * 16 + 2 * k) * CZ + z]);
      unsigned short hi = f2bf(sm.wl[(bh * 16 + 2 * k + 1) * CZ + z]);
      dw[k] = (unsigned int)lo | ((unsigned int)hi << 16);
    }
    unsigned int* dst =
        (unsigned int*)((char*)Wt + ((size_t)z * CH + a) * 64 + bh * 32);
    *(uint4*)dst = make_uint4(dw[0], dw[1], dw[2], dw[3]);
    *(uint4*)(dst + 4) = make_uint4(dw[4], dw[5], dw[6], dw[7]);
  }
}

// ---------------- Kernel 2: Tt[j][c] = sum_b Bbf[j,b] * Wt[c,b] (bf16 out) ----
__global__ __launch_bounds__(64) void tmat_kernel(
    const unsigned short* __restrict__ Bbf, const unsigned short* __restrict__ Wt,
    unsigned short* __restrict__ Tt) {
  int jt = blockIdx.x;   // 0..31 -> 16 j's
  int cq = blockIdx.y;   // 0..31 -> 8 c-tiles of 16
  int l = threadIdx.x;
  int q = l >> 4, r = l & 15;
  bf16x8 bfrag = *(const bf16x8*)(Bbf + (size_t)(jt * 16 + r) * CH + 8 * q);
  int j = jt * 16 + r;
  f32x4 zer = {0.f, 0.f, 0.f, 0.f};
  #pragma unroll
  for (int t = 0; t < 8; ++t) {
    int cbase = cq * 128 + t * 16;
    bf16x8 wfrag = *(const bf16x8*)(Wt + (size_t)(cbase + r) * CH + 8 * q);
    f32x4 acc = __builtin_amdgcn_mfma_f32_16x16x32_bf16(wfrag, bfrag, zer, 0, 0, 0);
    uint2 st;
    st.x = pk2(acc[0], acc[1]);
    st.y = pk2(acc[2], acc[3]);
    *(uint2*)(&Tt[(size_t)j * C4 + cbase + 4 * q]) = st;
  }
}

// ---------------- Probe: R8 outer's EXACT store geometry, write-only ----------
// Measures achievable write BW for the outer store pattern with no loads/MFMA.
// Writes bias values into a spare 128-MiB d_ws region (not d_out).
__global__ __launch_bounds__(512) void probe_kernel(
    const float* __restrict__ b_out, float* __restrict__ pout) {
  unsigned n = blockIdx.x;      // 0..255
  int jt = n & 7;
  int it = n >> 3;
  int tid = threadIdx.x;
  int w = tid >> 6, l = tid & 63, q = l >> 4, r = l & 15;
  int ib = it * 16;

  f32x4 bo[8];
  #pragma unroll
  for (int zt = 0; zt < 8; ++zt)
    bo[zt] = *(const f32x4*)(b_out + zt * 16 + 4 * q);

  int j0 = jt * 64 + w * 8;
  float* orow = pout + ((size_t)(ib + r) * LL) * CZ;

  #pragma unroll 2
  for (int jj = 0; jj < 8; ++jj) {
    int j = j0 + jj;
    float* oj = orow + (size_t)j * CZ;
    #pragma unroll
    for (int zt = 0; zt < 8; ++zt)
      *(f32x4*)(oj + zt * 16 + 4 * q) = bo[zt];
  }
}

// ---------------- Kernel 3: out[i,j,:] = A[i,:] . T[j,:,:] + b_out ------------
// R8 structure (best known): grid 256 (1 block/CU), 8 waves; block owns
// (16 i) x (64 j, XCD-affine jt); wave owns 8 consecutive j, loops serially.
__global__ __launch_bounds__(512) void outer_mfma(
    const unsigned short* __restrict__ Abf, const unsigned short* __restrict__ Tt,
    const float* __restrict__ b_out, float* __restrict__ out) {
  unsigned n = blockIdx.x;      // 0..255
  int jt = n & 7;               // XCD-affine j-tile (64 j each)
  int it = n >> 3;              // 0..31 -> 16 i each
  int tid = threadIdx.x;
  int w = tid >> 6, l = tid & 63, q = l >> 4, r = l & 15;
  int ib = it * 16;

  bf16x8 af = *(const bf16x8*)(Abf + (size_t)(ib + r) * CH + 8 * q);

  f32x4 bo[8];
  #pragma unroll
  for (int zt = 0; zt < 8; ++zt) bo[zt] = *(const f32x4*)(b_out + zt * 16 + 4 * q);

  int j0 = jt * 64 + w * 8;
  float* orow = out + ((size_t)(ib + r) * LL) * CZ;

  #pragma unroll 2
  for (int jj = 0; jj < 8; ++jj) {
    int j = j0 + jj;
    const unsigned short* Tj = Tt + (size_t)j * C4;
    float* oj = orow + (size_t)j * CZ;
    #pragma unroll
    for (int zt = 0; zt < 8; ++zt) {
      bf16x8 tf = *(const bf16x8*)(Tj + (size_t)(zt * 16 + r) * CH + 8 * q);
      // D = Tt^T(z x a) . A(a x i) + bias: col=r -> i, rows 4q+reg -> z.
      f32x4 d = __builtin_amdgcn_mfma_f32_16x16x32_bf16(tf, af, bo[zt], 0, 0, 0);
      *(f32x4*)(oj + zt * 16 + 4 * q) = d;
    }
  }
}

extern "C" void kernel_launch(void* const* d_in, const int* in_sizes, int n_in,
                              void* d_out, int out_size, void* d_ws, size_t ws_size,
                              hipStream_t stream) {
  const float* s     = (const float*)d_in[0];
  const float* gam   = (const float*)d_in[1];
  const float* bet   = (const float*)d_in[2];
  const float* w1    = (const float*)d_in[3];
  const float* b1    = (const float*)d_in[4];
  const float* w2    = (const float*)d_in[5];
  const float* b2    = (const float*)d_in[6];
  const float* w_out = (const float*)d_in[7];
  const float* b_out = (const float*)d_in[8];
  float* out = (float*)d_out;

  char* ws = (char*)d_ws;
  unsigned short* Abf = (unsigned short*)(ws);            // 32 KB
  unsigned short* Bbf = (unsigned short*)(ws + 32768);    // 32 KB
  unsigned short* Wt  = (unsigned short*)(ws + 65536);    // 256 KB
  unsigned short* Tt  = (unsigned short*)(ws + 327680);   // 4 MB
  float* probe_buf    = (float*)(ws + (8u << 20));        // 128 MiB probe region

  prep_kernel<<<LL + CH, 256, 0, stream>>>(s, gam, bet, w1, b1, w2, b2, w_out,
                                           Abf, Bbf, Wt);
  tmat_kernel<<<dim3(32, 32), 64, 0, stream>>>(Bbf, Wt, Tt);
  probe_kernel<<<256, 512, 0, stream>>>(b_out, probe_buf);
  outer_mfma<<<256, 512, 0, stream>>>(Abf, Tt, b_out, out);
}

// Round 13
// 43.486 us; speedup vs baseline: 2.5107x; 1.5091x over previous
//
#include <hip/hip_runtime.h>

#define CS 384
#define CH 32
#define CZ 128
#define LL 512
#define C4 (CZ * CH)   // 4096 combined (z,a) columns
#define EPSV 1e-5f

typedef __attribute__((ext_vector_type(8))) short bf16x8;
typedef __attribute__((ext_vector_type(4))) float f32x4;

static __device__ __forceinline__ unsigned short f2bf(float x) {
  union { float f; unsigned int u; } c; c.f = x;
  unsigned int r = c.u + 0x7FFFu + ((c.u >> 16) & 1u);  // RNE
  return (unsigned short)(r >> 16);
}
static __device__ __forceinline__ unsigned int pk2(float lo, float hi) {
  return (unsigned int)f2bf(lo) | ((unsigned int)f2bf(hi) << 16);
}

// ---------------- Kernel 1: [blocks 0..511] LayerNorm+proj -> bf16 A,B --------
// ----------------           [blocks 512..543] W transpose -> bf16 Wt ----------
__global__ __launch_bounds__(256) void prep_kernel(
    const float* __restrict__ s, const float* __restrict__ gamma,
    const float* __restrict__ beta,
    const float* __restrict__ w1, const float* __restrict__ b1,
    const float* __restrict__ w2, const float* __restrict__ b2,
    const float* __restrict__ w_out,
    unsigned short* __restrict__ Abf, unsigned short* __restrict__ Bbf,
    unsigned short* __restrict__ Wt) {
  __shared__ union {
    struct { float sn[CS]; float red[256]; float wred[8]; } ln;
    float wl[CH * CZ];
  } sm;
  int tid = threadIdx.x;

  if (blockIdx.x < LL) {
    int l = blockIdx.x;
    const float* srow = s + l * CS;
    float lsum = 0.f, lsq = 0.f;
    for (int c = tid; c < CS; c += 256) {
      float x = srow[c]; sm.ln.sn[c] = x; lsum += x; lsq += x * x;
    }
    #pragma unroll
    for (int off = 32; off > 0; off >>= 1) {
      lsum += __shfl_down(lsum, off);
      lsq  += __shfl_down(lsq, off);
    }
    int wv = tid >> 6;
    if ((tid & 63) == 0) { sm.ln.wred[wv] = lsum; sm.ln.wred[4 + wv] = lsq; }
    __syncthreads();
    float s1 = sm.ln.wred[0] + sm.ln.wred[1] + sm.ln.wred[2] + sm.ln.wred[3];
    float s2 = sm.ln.wred[4] + sm.ln.wred[5] + sm.ln.wred[6] + sm.ln.wred[7];
    float mu = s1 * (1.0f / CS);
    float var = s2 * (1.0f / CS) - mu * mu;
    float rstd = rsqrtf(var + EPSV);

    for (int c = tid; c < CS; c += 256)
      sm.ln.sn[c] = (sm.ln.sn[c] - mu) * rstd * gamma[c] + beta[c];
    __syncthreads();

    int o = tid & 63, q = tid >> 6;
    int h = o & 31;
    const float* w = (o < CH) ? w1 : w2;
    float acc = 0.f;
    int c0 = q * 96;
    #pragma unroll 8
    for (int c = c0; c < c0 + 96; ++c) acc += sm.ln.sn[c] * w[c * CH + h];
    sm.ln.red[tid] = acc; __syncthreads();
    if (tid < 64) {
      float r = sm.ln.red[tid] + sm.ln.red[tid + 64] + sm.ln.red[tid + 128] +
                sm.ln.red[tid + 192];
      if (o < CH) Abf[l * CH + h] = f2bf(r + b1[h]);
      else        Bbf[l * CH + h] = f2bf(r + b2[h]);
    }
  } else {
    int a = blockIdx.x - LL;  // 0..31
    const float4* Wg = (const float4*)(w_out + (size_t)a * CH * CZ);
    float4* Wl4 = (float4*)sm.wl;
    #pragma unroll
    for (int v = 0; v < 4; ++v) Wl4[tid + v * 256] = Wg[tid + v * 256];
    __syncthreads();
    int z = tid >> 1, bh = tid & 1;  // z 0..127, b-half 0..1
    unsigned int dw[8];
    #pragma unroll
    for (int k = 0; k < 8; ++k) {
      unsigned short lo = f2bf(sm.wl[(bh * 16 + 2 * k) * CZ + z]);
      unsigned short hi = f2bf(sm.wl[(bh * 16 + 2 * k + 1) * CZ + z]);
      dw[k] = (unsigned int)lo | ((unsigned int)hi << 16);
    }
    unsigned int* dst =
        (unsigned int*)((char*)Wt + ((size_t)z * CH + a) * 64 + bh * 32);
    *(uint4*)dst = make_uint4(dw[0], dw[1], dw[2], dw[3]);
    *(uint4*)(dst + 4) = make_uint4(dw[4], dw[5], dw[6], dw[7]);
  }
}

// ---------------- Kernel 2: Tt[j][c] = sum_b Bbf[j,b] * Wt[c,b] (bf16 out) ----
__global__ __launch_bounds__(64) void tmat_kernel(
    const unsigned short* __restrict__ Bbf, const unsigned short* __restrict__ Wt,
    unsigned short* __restrict__ Tt) {
  int jt = blockIdx.x;   // 0..31 -> 16 j's
  int cq = blockIdx.y;   // 0..31 -> 8 c-tiles of 16
  int l = threadIdx.x;
  int q = l >> 4, r = l & 15;
  bf16x8 bfrag = *(const bf16x8*)(Bbf + (size_t)(jt * 16 + r) * CH + 8 * q);
  int j = jt * 16 + r;
  f32x4 zer = {0.f, 0.f, 0.f, 0.f};
  #pragma unroll
  for (int t = 0; t < 8; ++t) {
    int cbase = cq * 128 + t * 16;
    bf16x8 wfrag = *(const bf16x8*)(Wt + (size_t)(cbase + r) * CH + 8 * q);
    f32x4 acc = __builtin_amdgcn_mfma_f32_16x16x32_bf16(wfrag, bfrag, zer, 0, 0, 0);
    uint2 st;
    st.x = pk2(acc[0], acc[1]);
    st.y = pk2(acc[2], acc[3]);
    *(uint2*)(&Tt[(size_t)j * C4 + cbase + 4 * q]) = st;
  }
}

// ---------------- Kernel 3: out[i,j,:] = A[i,:] . T[j,:,:] + b_out ------------
// WAVE-SPECIALIZED: waves 0-3 produce (Tt loads + MFMA -> LDS, double-buffered)
// waves 4-7 consume (ds_read -> contiguous 1-KB global stores, ZERO global
// loads in the storing waves -> store stream matches the R12 probe's 6 TB/s
// conditions). Block owns (16 i) x (64 j, XCD-affine jt); 17 uniform rounds.
__global__ __launch_bounds__(512) void outer_mfma(
    const unsigned short* __restrict__ Abf, const unsigned short* __restrict__ Tt,
    const float* __restrict__ b_out, float* __restrict__ out) {
  __shared__ float buf[2][4][16 * CZ];  // 2 x 4 x 8 KB = 64 KB
  unsigned n = blockIdx.x;      // 0..255
  int jt = n & 7;               // XCD-affine j-tile (64 j each)
  int it = n >> 3;              // 0..31 -> 16 i each
  int tid = threadIdx.x;
  int w = tid >> 6, l = tid & 63;
  int ib = it * 16;
  int j0 = jt * 64;

  if (w < 4) {
    // ---------------- Producer wave w: j = j0 + 4t + w ----------------
    int q = l >> 4, r = l & 15;
    bf16x8 af = *(const bf16x8*)(Abf + (size_t)(ib + r) * CH + 8 * q);
    f32x4 bo[8];
    #pragma unroll
    for (int zt = 0; zt < 8; ++zt)
      bo[zt] = *(const f32x4*)(b_out + zt * 16 + 4 * q);

    for (int t = 0; t <= 16; ++t) {
      if (t < 16) {
        int j = j0 + 4 * t + w;
        const unsigned short* Tj = Tt + (size_t)j * C4;
        float* myb = buf[t & 1][w];
        #pragma unroll
        for (int zt = 0; zt < 8; ++zt) {
          bf16x8 tf = *(const bf16x8*)(Tj + (size_t)(zt * 16 + r) * CH + 8 * q);
          // D = Tt^T(z x a) . A(a x i) + bias: col=r -> i, rows 4q+reg -> z.
          f32x4 d = __builtin_amdgcn_mfma_f32_16x16x32_bf16(tf, af, bo[zt], 0, 0, 0);
          int p = (4 * zt + q) ^ (r & 7);   // XOR-swizzled quad
          *(f32x4*)(myb + r * CZ + p * 4) = d;
        }
      }
      __syncthreads();
    }
  } else {
    // ---------------- Consumer wave c: stores round t-1's buffer ----------
    int c = w - 4;
    int lam = l & 31, half = l >> 5;
    for (int t = 0; t <= 16; ++t) {
      if (t >= 1) {
        int j = j0 + 4 * (t - 1) + c;
        const float* myb = buf[(t - 1) & 1][c];
        #pragma unroll
        for (int ip = 0; ip < 8; ++ip) {
          int row = 2 * ip + half;
          f32x4 v = *(const f32x4*)(myb + row * CZ + ((lam ^ (row & 7)) * 4));
          *(f32x4*)(out + ((size_t)(ib + row) * LL + j) * CZ + lam * 4) = v;
        }
      }
      __syncthreads();
    }
  }
}

extern "C" void kernel_launch(void* const* d_in, const int* in_sizes, int n_in,
                              void* d_out, int out_size, void* d_ws, size_t ws_size,
                              hipStream_t stream) {
  const float* s     = (const float*)d_in[0];
  const float* gam   = (const float*)d_in[1];
  const float* bet   = (const float*)d_in[2];
  const float* w1    = (const float*)d_in[3];
  const float* b1    = (const float*)d_in[4];
  const float* w2    = (const float*)d_in[5];
  const float* b2    = (const float*)d_in[6];
  const float* w_out = (const float*)d_in[7];
  const float* b_out = (const float*)d_in[8];
  float* out = (float*)d_out;

  char* ws = (char*)d_ws;
  unsigned short* Abf = (unsigned short*)(ws);            // 32 KB
  unsigned short* Bbf = (unsigned short*)(ws + 32768);    // 32 KB
  unsigned short* Wt  = (unsigned short*)(ws + 65536);    // 256 KB
  unsigned short* Tt  = (unsigned short*)(ws + 327680);   // 4 MB

  prep_kernel<<<LL + CH, 256, 0, stream>>>(s, gam, bet, w1, b1, w2, b2, w_out,
                                           Abf, Bbf, Wt);
  tmat_kernel<<<dim3(32, 32), 64, 0, stream>>>(Bbf, Wt, Tt);
  outer_mfma<<<256, 512, 0, stream>>>(Abf, Tt, b_out, out);
}

// Round 14
// 39.060 us; speedup vs baseline: 2.7952x; 1.1133x over previous
//
#include <hip/hip_runtime.h>

#define CS 384
#define CH 32
#define CZ 128
#define LL 512
#define C4 (CZ * CH)   // 4096 combined (z,a) columns
#define EPSV 1e-5f

typedef __attribute__((ext_vector_type(8))) short bf16x8;
typedef __attribute__((ext_vector_type(4))) float f32x4;

static __device__ __forceinline__ unsigned short f2bf(float x) {
  union { float f; unsigned int u; } c; c.f = x;
  unsigned int r = c.u + 0x7FFFu + ((c.u >> 16) & 1u);  // RNE
  return (unsigned short)(r >> 16);
}
static __device__ __forceinline__ unsigned int pk2(float lo, float hi) {
  return (unsigned int)f2bf(lo) | ((unsigned int)f2bf(hi) << 16);
}

// ---------------- Kernel 1: [blocks 0..511] LayerNorm+proj -> bf16 A,B --------
// ----------------           [blocks 512..543] W transpose -> bf16 Wt ----------
__global__ __launch_bounds__(256) void prep_kernel(
    const float* __restrict__ s, const float* __restrict__ gamma,
    const float* __restrict__ beta,
    const float* __restrict__ w1, const float* __restrict__ b1,
    const float* __restrict__ w2, const float* __restrict__ b2,
    const float* __restrict__ w_out,
    unsigned short* __restrict__ Abf, unsigned short* __restrict__ Bbf,
    unsigned short* __restrict__ Wt) {
  __shared__ union {
    struct { float sn[CS]; float red[256]; float wred[8]; } ln;
    float wl[CH * CZ];
  } sm;
  int tid = threadIdx.x;

  if (blockIdx.x < LL) {
    int l = blockIdx.x;
    const float* srow = s + l * CS;
    float lsum = 0.f, lsq = 0.f;
    for (int c = tid; c < CS; c += 256) {
      float x = srow[c]; sm.ln.sn[c] = x; lsum += x; lsq += x * x;
    }
    #pragma unroll
    for (int off = 32; off > 0; off >>= 1) {
      lsum += __shfl_down(lsum, off);
      lsq  += __shfl_down(lsq, off);
    }
    int wv = tid >> 6;
    if ((tid & 63) == 0) { sm.ln.wred[wv] = lsum; sm.ln.wred[4 + wv] = lsq; }
    __syncthreads();
    float s1 = sm.ln.wred[0] + sm.ln.wred[1] + sm.ln.wred[2] + sm.ln.wred[3];
    float s2 = sm.ln.wred[4] + sm.ln.wred[5] + sm.ln.wred[6] + sm.ln.wred[7];
    float mu = s1 * (1.0f / CS);
    float var = s2 * (1.0f / CS) - mu * mu;
    float rstd = rsqrtf(var + EPSV);

    for (int c = tid; c < CS; c += 256)
      sm.ln.sn[c] = (sm.ln.sn[c] - mu) * rstd * gamma[c] + beta[c];
    __syncthreads();

    int o = tid & 63, q = tid >> 6;
    int h = o & 31;
    const float* w = (o < CH) ? w1 : w2;
    float acc = 0.f;
    int c0 = q * 96;
    #pragma unroll 8
    for (int c = c0; c < c0 + 96; ++c) acc += sm.ln.sn[c] * w[c * CH + h];
    sm.ln.red[tid] = acc; __syncthreads();
    if (tid < 64) {
      float r = sm.ln.red[tid] + sm.ln.red[tid + 64] + sm.ln.red[tid + 128] +
                sm.ln.red[tid + 192];
      if (o < CH) Abf[l * CH + h] = f2bf(r + b1[h]);
      else        Bbf[l * CH + h] = f2bf(r + b2[h]);
    }
  } else {
    int a = blockIdx.x - LL;  // 0..31
    const float4* Wg = (const float4*)(w_out + (size_t)a * CH * CZ);
    float4* Wl4 = (float4*)sm.wl;
    #pragma unroll
    for (int v = 0; v < 4; ++v) Wl4[tid + v * 256] = Wg[tid + v * 256];
    __syncthreads();
    int z = tid >> 1, bh = tid & 1;  // z 0..127, b-half 0..1
    unsigned int dw[8];
    #pragma unroll
    for (int k = 0; k < 8; ++k) {
      unsigned short lo = f2bf(sm.wl[(bh * 16 + 2 * k) * CZ + z]);
      unsigned short hi = f2bf(sm.wl[(bh * 16 + 2 * k + 1) * CZ + z]);
      dw[k] = (unsigned int)lo | ((unsigned int)hi << 16);
    }
    unsigned int* dst =
        (unsigned int*)((char*)Wt + ((size_t)z * CH + a) * 64 + bh * 32);
    *(uint4*)dst = make_uint4(dw[0], dw[1], dw[2], dw[3]);
    *(uint4*)(dst + 4) = make_uint4(dw[4], dw[5], dw[6], dw[7]);
  }
}

// ---------------- Kernel 2: Tt[j][c] = sum_b Bbf[j,b] * Wt[c,b] (bf16 out) ----
__global__ __launch_bounds__(64) void tmat_kernel(
    const unsigned short* __restrict__ Bbf, const unsigned short* __restrict__ Wt,
    unsigned short* __restrict__ Tt) {
  int jt = blockIdx.x;   // 0..31 -> 16 j's
  int cq = blockIdx.y;   // 0..31 -> 8 c-tiles of 16
  int l = threadIdx.x;
  int q = l >> 4, r = l & 15;
  bf16x8 bfrag = *(const bf16x8*)(Bbf + (size_t)(jt * 16 + r) * CH + 8 * q);
  int j = jt * 16 + r;
  f32x4 zer = {0.f, 0.f, 0.f, 0.f};
  #pragma unroll
  for (int t = 0; t < 8; ++t) {
    int cbase = cq * 128 + t * 16;
    bf16x8 wfrag = *(const bf16x8*)(Wt + (size_t)(cbase + r) * CH + 8 * q);
    f32x4 acc = __builtin_amdgcn_mfma_f32_16x16x32_bf16(wfrag, bfrag, zer, 0, 0, 0);
    uint2 st;
    st.x = pk2(acc[0], acc[1]);
    st.y = pk2(acc[2], acc[3]);
    *(uint2*)(&Tt[(size_t)j * C4 + cbase + 4 * q]) = st;
  }
}

// ---------------- Kernel 3: out[i,j,:] = A[i,:] . T[j,:,:] + b_out ------------
// Wave-specialized, FLAG-HANDSHAKE (no __syncthreads in the loop): waves 0-3
// produce (Tt loads + MFMA -> LDS dbuf); waves 4-7 consume (ds_read ->
// contiguous stores). The storing waves execute NO vmcnt wait anywhere, so
// the store queue stays at full depth (63 outstanding). Sync = volatile LDS
// counters + s_sleep spin (lgkmcnt only; vmcnt untouched).
__global__ __launch_bounds__(512) void outer_mfma(
    const unsigned short* __restrict__ Abf, const unsigned short* __restrict__ Tt,
    const float* __restrict__ b_out, float* __restrict__ out) {
  __shared__ float buf[2][4][16 * CZ];  // 2 x 4 x 8 KB = 64 KB
  __shared__ int prodf[4];              // producer progress (rounds done)
  __shared__ int consf[4];              // consumer progress (rounds done)
  unsigned n = blockIdx.x;      // 0..255
  int jt = n & 7;               // XCD-affine j-tile (64 j each)
  int it = n >> 3;              // 0..31 -> 16 i each
  int tid = threadIdx.x;
  int w = tid >> 6, l = tid & 63;
  int ib = it * 16;
  int j0 = jt * 64;

  if (tid < 4) { prodf[tid] = 0; consf[tid] = 0; }
  __syncthreads();  // only barrier; no stores outstanding yet

  if (w < 4) {
    // ---------------- Producer wave w: j = j0 + 4t + w ----------------
    int q = l >> 4, r = l & 15;
    bf16x8 af = *(const bf16x8*)(Abf + (size_t)(ib + r) * CH + 8 * q);
    f32x4 bo[8];
    #pragma unroll
    for (int zt = 0; zt < 8; ++zt)
      bo[zt] = *(const f32x4*)(b_out + zt * 16 + 4 * q);

    for (int t = 0; t < 16; ++t) {
      // buffer t&1 is free once consumer finished round t-2.
      while (*(volatile int*)&consf[w] < t - 1) __builtin_amdgcn_s_sleep(2);
      int j = j0 + 4 * t + w;
      const unsigned short* Tj = Tt + (size_t)j * C4;
      float* myb = buf[t & 1][w];
      #pragma unroll
      for (int zt = 0; zt < 8; ++zt) {
        bf16x8 tf = *(const bf16x8*)(Tj + (size_t)(zt * 16 + r) * CH + 8 * q);
        // D = Tt^T(z x a) . A(a x i) + bias: col=r -> i, rows 4q+reg -> z.
        f32x4 d = __builtin_amdgcn_mfma_f32_16x16x32_bf16(tf, af, bo[zt], 0, 0, 0);
        int p = (4 * zt + q) ^ (r & 7);   // XOR-swizzled quad
        *(f32x4*)(myb + r * CZ + p * 4) = d;
      }
      asm volatile("s_waitcnt lgkmcnt(0)" ::: "memory");  // LDS data visible
      if (l == 0) *(volatile int*)&prodf[w] = t + 1;
    }
  } else {
    // ---------------- Consumer wave c: ds_read -> stores, NO vmcnt waits -----
    int c = w - 4;
    int lam = l & 31, half = l >> 5;
    for (int t = 0; t < 16; ++t) {
      while (*(volatile int*)&prodf[c] < t + 1) __builtin_amdgcn_s_sleep(2);
      int j = j0 + 4 * t + c;
      const float* myb = buf[t & 1][c];
      #pragma unroll
      for (int ip = 0; ip < 8; ++ip) {
        int row = 2 * ip + half;
        f32x4 v = *(const f32x4*)(myb + row * CZ + ((lam ^ (row & 7)) * 4));
        *(f32x4*)(out + ((size_t)(ib + row) * LL + j) * CZ + lam * 4) = v;
      }
      asm volatile("s_waitcnt lgkmcnt(0)" ::: "memory");  // reads landed in regs
      if (l == 0) *(volatile int*)&consf[c] = t + 1;
    }
  }
}

extern "C" void kernel_launch(void* const* d_in, const int* in_sizes, int n_in,
                              void* d_out, int out_size, void* d_ws, size_t ws_size,
                              hipStream_t stream) {
  const float* s     = (const float*)d_in[0];
  const float* gam   = (const float*)d_in[1];
  const float* bet   = (const float*)d_in[2];
  const float* w1    = (const float*)d_in[3];
  const float* b1    = (const float*)d_in[4];
  const float* w2    = (const float*)d_in[5];
  const float* b2    = (const float*)d_in[6];
  const float* w_out = (const float*)d_in[7];
  const float* b_out = (const float*)d_in[8];
  float* out = (float*)d_out;

  char* ws = (char*)d_ws;
  unsigned short* Abf = (unsigned short*)(ws);            // 32 KB
  unsigned short* Bbf = (unsigned short*)(ws + 32768);    // 32 KB
  unsigned short* Wt  = (unsigned short*)(ws + 65536);    // 256 KB
  unsigned short* Tt  = (unsigned short*)(ws + 327680);   // 4 MB

  prep_kernel<<<LL + CH, 256, 0, stream>>>(s, gam, bet, w1, b1, w2, b2, w_out,
                                           Abf, Bbf, Wt);
  tmat_kernel<<<dim3(32, 32), 64, 0, stream>>>(Bbf, Wt, Tt);
  outer_mfma<<<256, 512, 0, stream>>>(Abf, Tt, b_out, out);
}